// Round 8
// baseline (322.140 us; speedup 1.0000x reference)
//
#include <hip/hip_runtime.h>
#include <cstdint>
#include <cstddef>

// ---------------------------------------------------------------------------
// MambaBlock on MI355X (gfx950).
// cast_multi -> G1(256x128 triple-buffered single-barrier, fused bf16
// epilogue) -> conv(bf16) -> G2(K-split) -> reduce -> G3(softplus) ->
// scan(A,B,C; CHUNK=64) -> G4(128sq triple-buffered, fused bias)
// ---------------------------------------------------------------------------

typedef __bf16 bf16x8 __attribute__((ext_vector_type(8)));
typedef float f32x4 __attribute__((ext_vector_type(4)));

#define GLDS16(g, l)                                        \
  __builtin_amdgcn_global_load_lds(                         \
      (__attribute__((address_space(1))) void*)(g),         \
      (__attribute__((address_space(3))) void*)(l), 16, 0, 0)

#define FENCE() asm volatile("" ::: "memory")
#define BARRIER()                      \
  do {                                 \
    FENCE();                           \
    __builtin_amdgcn_s_barrier();      \
    FENCE();                           \
  } while (0)

static __device__ __forceinline__ unsigned short f2b(float f) {
  unsigned int x = __builtin_bit_cast(unsigned int, f);
  x += 0x7fffu + ((x >> 16) & 1u);
  return (unsigned short)(x >> 16);
}

static __device__ __forceinline__ float b2f(unsigned short u) {
  return __builtin_bit_cast(float, (unsigned int)u << 16);
}

static __device__ __forceinline__ float sigmoidf_fast(float x) {
  return 1.0f / (1.0f + __expf(-x));
}

// ---------------- merged cast fp32 -> bf16 (5 segments, one launch) --------
struct CastArgs {
  const float* src[5];
  unsigned short* dst[5];
  int n4[5];
};

__global__ __launch_bounds__(256) void cast_multi(CastArgs a) {
  const int stride = gridDim.x * 256;
  const int t = blockIdx.x * 256 + threadIdx.x;
#pragma unroll
  for (int k = 0; k < 5; ++k) {
    const float4* src = reinterpret_cast<const float4*>(a.src[k]);
    ushort4* dst = reinterpret_cast<ushort4*>(a.dst[k]);
    const int n4 = a.n4[k];
    for (int i = t; i < n4; i += stride) {
      float4 v = src[i];
      ushort4 o;
      o.x = f2b(v.x); o.y = f2b(v.y); o.z = f2b(v.z); o.w = f2b(v.w);
      dst[i] = o;
    }
  }
}

// ---------------- G1: 256x128 tile, BK=64, 8 waves, TRIPLE buffer ----------
// Single barrier per K-tile: stage(kt+2) targets buf[(kt+2)%3] which held
// kt-1, fully consumed before this iter's entry barrier.  No lgkmcnt drain;
// compiler fine-grained waits let waves' reads overlap other waves' MFMAs.
// Fused epilogue: v = acc+bias; col<4096 -> xib bf16; col>=4096 -> silu->rsb.
__global__ __launch_bounds__(512) void gemmG1(
    const unsigned short* __restrict__ A, const unsigned short* __restrict__ B,
    unsigned short* __restrict__ xib, unsigned short* __restrict__ rsb,
    const float* __restrict__ bias, int M, int N, int K) {
  // 3 bufs x (A 256x64 = 32KB + B 128x64 = 16KB) = 144KB
  __shared__ __align__(16) unsigned short lds[73728];
  const int tid = threadIdx.x;
  const int l = tid & 63;
  const int w = tid >> 6;       // 0..7
  const int wr = w >> 1;        // 0..3 -> 64-row strip
  const int wc = w & 1;         // 0..1 -> 64-col strip

  // T1: bijective XCD swizzle (nwg = 512, %8==0)
  const int nwg = gridDim.x * gridDim.y;
  const int q = nwg >> 3;
  int flat = blockIdx.x + gridDim.x * blockIdx.y;
  flat = (flat & 7) * q + (flat >> 3);
  const int bx = flat % gridDim.x;
  const int by = flat / gridDim.x;

  const long brow = (long)bx * 256;
  const long bcol = (long)by * 128;
  const int NT = K >> 6;

  f32x4 acc[4][4] = {};

  const unsigned short* Ab = A + (size_t)brow * K;
  const unsigned short* Bb = B + (size_t)bcol * K;

  // staging offsets: pre-swizzled global source (slot ^= row&7), linear LDS.
  size_t soffA[4], soffB[2];
  int doffA[4], doffB[2];
#pragma unroll
  for (int i = 0; i < 4; ++i) {
    int idx = i * 512 + tid;       // 0..2047 -> row 0..255
    int r = idx >> 3, s = idx & 7;
    soffA[i] = (size_t)r * K + (size_t)((s ^ (r & 7)) << 3);
    doffA[i] = idx * 8;
  }
#pragma unroll
  for (int i = 0; i < 2; ++i) {
    int idx = i * 512 + tid;       // 0..1023 -> row 0..127
    int r = idx >> 3, s = idx & 7;
    soffB[i] = (size_t)r * K + (size_t)((s ^ (r & 7)) << 3);
    doffB[i] = idx * 8;
  }

  auto stage = [&](int kt) {
    const int bb = (kt % 3) * 24576;
    const int k0 = kt << 6;
#pragma unroll
    for (int i = 0; i < 4; ++i) GLDS16(Ab + soffA[i] + k0, &lds[bb + doffA[i]]);
#pragma unroll
    for (int i = 0; i < 2; ++i) GLDS16(Bb + soffB[i] + k0, &lds[bb + 16384 + doffB[i]]);
  };

  const int la = l & 15, hi = l >> 4, lo7 = l & 7;
  const int sw0 = (hi ^ lo7) << 3;
  const int sw1 = ((hi + 4) ^ lo7) << 3;
  const int rowA = wr * 64 + la;
  const int colB = wc * 64 + la;

  stage(0);
  stage(1);

  for (int kt = 0; kt < NT; ++kt) {
    if (kt + 1 < NT) asm volatile("s_waitcnt vmcnt(6)" ::: "memory");
    else             asm volatile("s_waitcnt vmcnt(0)" ::: "memory");
    BARRIER();  // kt's data landed; all waves consumed buf[(kt+2)%3] (= kt-1)
    const int bb = (kt % 3) * 24576;
    bf16x8 af[4][2], bf[4][2];
#pragma unroll
    for (int mt = 0; mt < 4; ++mt) {
      af[mt][0] = *reinterpret_cast<const bf16x8*>(&lds[bb + (rowA + mt * 16) * 64 + sw0]);
      af[mt][1] = *reinterpret_cast<const bf16x8*>(&lds[bb + (rowA + mt * 16) * 64 + sw1]);
    }
#pragma unroll
    for (int nt = 0; nt < 4; ++nt) {
      bf[nt][0] = *reinterpret_cast<const bf16x8*>(&lds[bb + 16384 + (colB + nt * 16) * 64 + sw0]);
      bf[nt][1] = *reinterpret_cast<const bf16x8*>(&lds[bb + 16384 + (colB + nt * 16) * 64 + sw1]);
    }
    if (kt + 2 < NT) stage(kt + 2);
    __builtin_amdgcn_s_setprio(1);
#pragma unroll
    for (int kk = 0; kk < 2; ++kk)
#pragma unroll
      for (int mt = 0; mt < 4; ++mt)
#pragma unroll
        for (int nt = 0; nt < 4; ++nt)
          acc[mt][nt] = __builtin_amdgcn_mfma_f32_16x16x32_bf16(
              af[mt][kk], bf[nt][kk], acc[mt][nt], 0, 0, 0);
    __builtin_amdgcn_s_setprio(0);
  }

  // epilogue: C/D layout col=lane&15, row=(lane>>4)*4+reg
  const long r0 = brow + wr * 64 + (l >> 4) * 4;
  const long c0 = bcol + wc * 64 + (l & 15);
#pragma unroll
  for (int mt = 0; mt < 4; ++mt) {
#pragma unroll
    for (int nt = 0; nt < 4; ++nt) {
      const long col = c0 + nt * 16;
      const float bv = bias[col];
      const bool isres = col >= 4096;
      const long cc = isres ? col - 4096 : col;
#pragma unroll
      for (int r = 0; r < 4; ++r) {
        float v = acc[mt][nt][r] + bv;
        if (isres) {
          float s = v * sigmoidf_fast(v);
          rsb[(r0 + mt * 16 + r) * 4096 + cc] = f2b(s);
        } else {
          xib[(r0 + mt * 16 + r) * 4096 + cc] = f2b(v);
        }
      }
    }
  }
}

// ---------------- G4: 128x128 tile, BK=64, 8 waves, TRIPLE buffer ----------
// Same single-barrier structure; 3 x 32KB = 96KB LDS; fused bias, fp32 out.
__global__ __launch_bounds__(512) void gemm128_bt(
    const unsigned short* __restrict__ A, const unsigned short* __restrict__ B,
    float* __restrict__ C, const float* __restrict__ bias,
    int M, int N, int K) {
  __shared__ __align__(16) unsigned short lds[49152];  // 3 x (A 16KB + B 16KB)
  const int tid = threadIdx.x;
  const int l = tid & 63;
  const int w = tid >> 6;       // 0..7
  const int wr = w >> 2;        // 0..1 -> 64-row half
  const int wc = w & 3;         // 0..3 -> 32-col quarter

  const int nwg = gridDim.x * gridDim.y;
  const int q = nwg >> 3;
  int flat = blockIdx.x + gridDim.x * blockIdx.y;
  flat = (flat & 7) * q + (flat >> 3);
  const int bx = flat % gridDim.x;
  const int by = flat / gridDim.x;

  const long brow = (long)bx * 128;
  const long bcol = (long)by * 128;
  const int NT = K >> 6;

  f32x4 acc[4][2] = {};

  const unsigned short* Ab = A + (size_t)brow * K;
  const unsigned short* Bb = B + (size_t)bcol * K;
  size_t soff[2];
  int doff[2];
#pragma unroll
  for (int i = 0; i < 2; ++i) {
    int idx = i * 512 + tid;      // 0..1023 -> row 0..127
    int r = idx >> 3, s = idx & 7;
    soff[i] = (size_t)r * K + (size_t)((s ^ (r & 7)) << 3);
    doff[i] = idx * 8;
  }

  auto stage = [&](int kt) {
    const int bb = (kt % 3) * 16384;
    const int k0 = kt << 6;
#pragma unroll
    for (int i = 0; i < 2; ++i) GLDS16(Ab + soff[i] + k0, &lds[bb + doff[i]]);
#pragma unroll
    for (int i = 0; i < 2; ++i) GLDS16(Bb + soff[i] + k0, &lds[bb + 8192 + doff[i]]);
  };

  const int la = l & 15, hi = l >> 4, lo7 = l & 7;
  const int sw0 = (hi ^ lo7) << 3;
  const int sw1 = ((hi + 4) ^ lo7) << 3;
  const int rowA = wr * 64 + la;
  const int colB = wc * 32 + la;

  stage(0);
  stage(1);

  for (int kt = 0; kt < NT; ++kt) {
    if (kt + 1 < NT) asm volatile("s_waitcnt vmcnt(4)" ::: "memory");
    else             asm volatile("s_waitcnt vmcnt(0)" ::: "memory");
    BARRIER();
    const int bb = (kt % 3) * 16384;
    bf16x8 af[4][2], bf[2][2];
#pragma unroll
    for (int mt = 0; mt < 4; ++mt) {
      af[mt][0] = *reinterpret_cast<const bf16x8*>(&lds[bb + (rowA + mt * 16) * 64 + sw0]);
      af[mt][1] = *reinterpret_cast<const bf16x8*>(&lds[bb + (rowA + mt * 16) * 64 + sw1]);
    }
#pragma unroll
    for (int nt = 0; nt < 2; ++nt) {
      bf[nt][0] = *reinterpret_cast<const bf16x8*>(&lds[bb + 8192 + (colB + nt * 16) * 64 + sw0]);
      bf[nt][1] = *reinterpret_cast<const bf16x8*>(&lds[bb + 8192 + (colB + nt * 16) * 64 + sw1]);
    }
    if (kt + 2 < NT) stage(kt + 2);
    __builtin_amdgcn_s_setprio(1);
#pragma unroll
    for (int kk = 0; kk < 2; ++kk)
#pragma unroll
      for (int mt = 0; mt < 4; ++mt)
#pragma unroll
        for (int nt = 0; nt < 2; ++nt)
          acc[mt][nt] = __builtin_amdgcn_mfma_f32_16x16x32_bf16(
              af[mt][kk], bf[nt][kk], acc[mt][nt], 0, 0, 0);
    __builtin_amdgcn_s_setprio(0);
  }

  const long r0 = brow + wr * 64 + (l >> 4) * 4;
  const long c0 = bcol + wc * 32 + (l & 15);
#pragma unroll
  for (int mt = 0; mt < 4; ++mt) {
#pragma unroll
    for (int nt = 0; nt < 2; ++nt) {
      long col = c0 + nt * 16;
      float bv = bias[col];
#pragma unroll
      for (int r = 0; r < 4; ++r)
        C[(r0 + mt * 16 + r) * (long)N + col] = acc[mt][nt][r] + bv;
    }
  }
}

// ---------------- G3: softplus GEMM (m97 structure, 128x128) ----------------
__global__ __launch_bounds__(256) void gemm_bt_sp(
    const unsigned short* __restrict__ A, const unsigned short* __restrict__ B,
    float* __restrict__ C, int M, int N, int K) {
  __shared__ __align__(16) unsigned short lA[128 * 32];
  __shared__ __align__(16) unsigned short lB[128 * 32];
  const int tid = threadIdx.x;
  const int l = tid & 63;
  const int w = tid >> 6;
  const int wr = w >> 1, wc = w & 1;
  const long brow = (long)blockIdx.x * 128;
  const long bcol = (long)blockIdx.y * 128;

  f32x4 acc[4][4] = {};

  const int srow = tid >> 2;
  const int scol = (tid & 3) * 8;

  const unsigned short* Ab = A + (size_t)brow * K;
  const unsigned short* Bb = B + (size_t)bcol * K;

  for (int k0 = 0; k0 < K; k0 += 32) {
#pragma unroll
    for (int j = 0; j < 2; ++j) {
      GLDS16(Ab + (size_t)(j * 64 + srow) * K + k0 + scol, &lA[j * 2048 + tid * 8]);
      GLDS16(Bb + (size_t)(j * 64 + srow) * K + k0 + scol, &lB[j * 2048 + tid * 8]);
    }
    __syncthreads();
    bf16x8 af[4], bfr[4];
#pragma unroll
    for (int mt = 0; mt < 4; ++mt)
      af[mt] = *reinterpret_cast<const bf16x8*>(
          &lA[(wr * 64 + mt * 16 + (l & 15)) * 32 + (l >> 4) * 8]);
#pragma unroll
    for (int nt = 0; nt < 4; ++nt)
      bfr[nt] = *reinterpret_cast<const bf16x8*>(
          &lB[(wc * 64 + nt * 16 + (l & 15)) * 32 + (l >> 4) * 8]);
#pragma unroll
    for (int mt = 0; mt < 4; ++mt)
#pragma unroll
      for (int nt = 0; nt < 4; ++nt)
        acc[mt][nt] = __builtin_amdgcn_mfma_f32_16x16x32_bf16(
            af[mt], bfr[nt], acc[mt][nt], 0, 0, 0);
    __syncthreads();
  }

  const long r0 = brow + wr * 64 + ((l >> 4) * 4);
  const long c0 = bcol + wc * 64 + (l & 15);
#pragma unroll
  for (int mt = 0; mt < 4; ++mt) {
#pragma unroll
    for (int nt = 0; nt < 4; ++nt) {
      long col = c0 + nt * 16;
#pragma unroll
      for (int r = 0; r < 4; ++r) {
        long row = r0 + mt * 16 + r;
        float v = acc[mt][nt][r];
        v = (v > 20.0f) ? v : log1pf(__expf(v));
        C[row * (long)N + col] = v;
      }
    }
  }
}

// ---------------- depthwise causal conv1d (k=4) + SiLU, bf16 in/out --------
__global__ __launch_bounds__(256) void conv_silu_k(
    const unsigned short* __restrict__ xib, const float* __restrict__ cw,
    const float* __restrict__ cb, unsigned short* __restrict__ xcb) {
  const int d = blockIdx.x * 256 + threadIdx.x;  // 0..4095
  const int t0 = blockIdx.y * 128;
  const float4 wv = *reinterpret_cast<const float4*>(cw + (size_t)d * 4);
  const float bv = cb[d];
  float xm3 = (t0 >= 3) ? b2f(xib[(size_t)(t0 - 3) * 4096 + d]) : 0.0f;
  float xm2 = (t0 >= 2) ? b2f(xib[(size_t)(t0 - 2) * 4096 + d]) : 0.0f;
  float xm1 = (t0 >= 1) ? b2f(xib[(size_t)(t0 - 1) * 4096 + d]) : 0.0f;
  for (int tt = 0; tt < 128; ++tt) {
    const size_t t = (size_t)t0 + tt;
    float xt = b2f(xib[t * 4096 + d]);
    float a = bv + wv.x * xm3 + wv.y * xm2 + wv.z * xm1 + wv.w * xt;
    float s = a * sigmoidf_fast(a);
    xcb[t * 4096 + d] = f2b(s);
    xm3 = xm2; xm2 = xm1; xm1 = xt;
  }
}

// ---------------- G2: dbc partials, K-split x8 ----------------
__global__ __launch_bounds__(256) void gemm_dbc(
    const unsigned short* __restrict__ A, const unsigned short* __restrict__ B,
    float* __restrict__ part) {
  __shared__ __align__(16) unsigned short lA[64 * 32];
  __shared__ __align__(16) unsigned short lB[160 * 32];
  const int tid = threadIdx.x;
  const int l = tid & 63, w = tid >> 6;
  const int brow = blockIdx.x * 64;
  const int ks = blockIdx.y;
  const int K = 4096;
  f32x4 acc[10] = {};
  const int srow = tid >> 2, scol = (tid & 3) * 8;
  for (int k0 = ks * 512; k0 < ks * 512 + 512; k0 += 32) {
    GLDS16(A + (size_t)(brow + srow) * K + k0 + scol, &lA[tid * 8]);
#pragma unroll
    for (int j = 0; j < 3; ++j) {
      int li = j * 256 + tid;
      if (li < 640) {
        GLDS16(B + (size_t)(li >> 2) * K + k0 + (li & 3) * 8, &lB[li * 8]);
      }
    }
    __syncthreads();
    bf16x8 af = *reinterpret_cast<const bf16x8*>(
        &lA[(w * 16 + (l & 15)) * 32 + (l >> 4) * 8]);
#pragma unroll
    for (int nt = 0; nt < 10; ++nt) {
      bf16x8 bfr = *reinterpret_cast<const bf16x8*>(
          &lB[(nt * 16 + (l & 15)) * 32 + (l >> 4) * 8]);
      acc[nt] = __builtin_amdgcn_mfma_f32_16x16x32_bf16(af, bfr, acc[nt], 0, 0, 0);
    }
    __syncthreads();
  }
  const int r0 = brow + w * 16 + (l >> 4) * 4;
  const int c = l & 15;
#pragma unroll
  for (int nt = 0; nt < 10; ++nt)
#pragma unroll
    for (int r = 0; r < 4; ++r)
      part[((size_t)ks * 2048 + r0 + r) * 160 + nt * 16 + c] = acc[nt][r];
}

__global__ __launch_bounds__(256) void reduce_dbc(
    const float* __restrict__ part, unsigned short* __restrict__ drb,
    float* __restrict__ bc) {
  int idx = blockIdx.x * 256 + threadIdx.x;
  float s = 0.0f;
#pragma unroll
  for (int k = 0; k < 8; ++k) s += part[(size_t)k * 2048 * 160 + idx];
  int row = idx / 160, col = idx - row * 160;
  if (col < 128) drb[row * 128 + col] = f2b(s);
  else bc[row * 32 + (col - 128)] = s;
}

// ---------------- chunked selective scan (CHUNK=64, u from bf16) -----------
__global__ __launch_bounds__(256) void scan_passA(
    const float* __restrict__ delta, const unsigned short* __restrict__ xcb,
    const float* __restrict__ bc, const float* __restrict__ alog,
    float* __restrict__ P, float* __restrict__ S) {
  __shared__ float lbc[2048];
  const int d = blockIdx.x * 256 + threadIdx.x;
  const int c = blockIdx.y;
  const int t0 = c * 64;
#pragma unroll
  for (int j = 0; j < 8; ++j) {
    int idx = j * 256 + threadIdx.x;
    lbc[idx] = bc[(size_t)t0 * 32 + idx];
  }
  __syncthreads();
  float a[16], h[16], p[16];
#pragma unroll
  for (int s = 0; s < 16; ++s) {
    a[s] = -__expf(alog[(size_t)d * 16 + s]);
    h[s] = 0.0f;
    p[s] = 1.0f;
  }
  for (int tt = 0; tt < 64; ++tt) {
    float dt = delta[(size_t)(t0 + tt) * 4096 + d];
    float u = b2f(xcb[(size_t)(t0 + tt) * 4096 + d]);
    float du = dt * u;
#pragma unroll
    for (int s = 0; s < 16; ++s) {
      float e = __expf(dt * a[s]);
      h[s] = e * h[s] + du * lbc[tt * 32 + s];
      p[s] *= e;
    }
  }
  size_t o = ((size_t)c * 4096 + d) * 16;
#pragma unroll
  for (int s = 0; s < 16; s += 4) {
    *reinterpret_cast<float4*>(&P[o + s]) = make_float4(p[s], p[s + 1], p[s + 2], p[s + 3]);
    *reinterpret_cast<float4*>(&S[o + s]) = make_float4(h[s], h[s + 1], h[s + 2], h[s + 3]);
  }
}

__global__ __launch_bounds__(256) void scan_passB(
    float* __restrict__ P, const float* __restrict__ S) {
  const int idx = blockIdx.x * 256 + threadIdx.x;
  float h = 0.0f;
  for (int c = 0; c < 32; ++c) {
    size_t o = (size_t)c * 65536 + idx;
    float p = P[o], sv = S[o];
    P[o] = h;
    h = p * h + sv;
  }
}

__global__ __launch_bounds__(256) void scan_passC(
    const float* __restrict__ delta, const unsigned short* __restrict__ xcb,
    const float* __restrict__ bc, const float* __restrict__ alog,
    const float* __restrict__ hst, const float* __restrict__ Dp,
    const unsigned short* __restrict__ rsb, unsigned short* __restrict__ yb) {
  __shared__ float lbc[2048];
  const int d = blockIdx.x * 256 + threadIdx.x;
  const int c = blockIdx.y;
  const int t0 = c * 64;
#pragma unroll
  for (int j = 0; j < 8; ++j) {
    int idx = j * 256 + threadIdx.x;
    lbc[idx] = bc[(size_t)t0 * 32 + idx];
  }
  __syncthreads();
  float a[16], h[16];
  size_t o = ((size_t)c * 4096 + d) * 16;
#pragma unroll
  for (int s = 0; s < 16; ++s) {
    a[s] = -__expf(alog[(size_t)d * 16 + s]);
    h[s] = hst[o + s];
  }
  const float Dv = Dp[d];
  for (int tt = 0; tt < 64; ++tt) {
    float dt = delta[(size_t)(t0 + tt) * 4096 + d];
    float u = b2f(xcb[(size_t)(t0 + tt) * 4096 + d]);
    float du = dt * u;
    float y = 0.0f;
#pragma unroll
    for (int s = 0; s < 16; ++s) {
      float e = __expf(dt * a[s]);
      h[s] = e * h[s] + du * lbc[tt * 32 + s];
      y += h[s] * lbc[tt * 32 + 16 + s];
    }
    float rs = b2f(rsb[(size_t)(t0 + tt) * 4096 + d]);  // silu(res), precomputed
    float v = (y + u * Dv) * rs;
    yb[(size_t)(t0 + tt) * 4096 + d] = f2b(v);
  }
}

// ---------------------------------------------------------------------------
extern "C" void kernel_launch(void* const* d_in, const int* in_sizes, int n_in,
                              void* d_out, int out_size, void* d_ws, size_t ws_size,
                              hipStream_t stream) {
  const float* x    = (const float*)d_in[0];
  const float* w1   = (const float*)d_in[1];
  const float* b1   = (const float*)d_in[2];
  const float* cw   = (const float*)d_in[3];
  const float* cb   = (const float*)d_in[4];
  const float* w2   = (const float*)d_in[5];
  const float* w3   = (const float*)d_in[6];
  const float* alog = (const float*)d_in[7];
  const float* Dp   = (const float*)d_in[8];
  const float* w4   = (const float*)d_in[9];
  const float* b4   = (const float*)d_in[10];
  float* out = (float*)d_out;

  char* ws = (char*)d_ws;
  size_t off = 0;
  auto alloc = [&](size_t b) {
    size_t o = off;
    off += (b + 255) & ~(size_t)255;
    return o;
  };
  unsigned short* w1b = (unsigned short*)(ws + alloc(2ull * 8192 * 2048));
  unsigned short* xb  = (unsigned short*)(ws + alloc(2ull * 2048 * 2048));
  unsigned short* w2b = (unsigned short*)(ws + alloc(2ull * 160 * 4096));
  unsigned short* w3b = (unsigned short*)(ws + alloc(2ull * 4096 * 128));
  unsigned short* w4b = (unsigned short*)(ws + alloc(2ull * 2048 * 4096));
  unsigned short* xib = (unsigned short*)(ws + alloc(2ull * 2048 * 4096));
  unsigned short* rsb = (unsigned short*)(ws + alloc(2ull * 2048 * 4096));
  unsigned short* xcb = (unsigned short*)(ws + alloc(2ull * 2048 * 4096));
  unsigned short* drb = (unsigned short*)(ws + alloc(2ull * 2048 * 128));
  float* bcb  = (float*)(ws + alloc(4ull * 2048 * 32));
  float* delta = (float*)(ws + alloc(4ull * 2048 * 4096));
  float* P = (float*)(ws + alloc(4ull * 32 * 4096 * 16));
  float* S = (float*)(ws + alloc(4ull * 32 * 4096 * 16));
  float* part  = delta;                 // G2 partials (10.5MB), consumed pre-G3
  unsigned short* yb = xib;             // xib dead after conv

  if (ws_size < off) return;

  CastArgs ca;
  ca.src[0] = w1; ca.dst[0] = w1b; ca.n4[0] = 8192 * 2048 / 4;
  ca.src[1] = x;  ca.dst[1] = xb;  ca.n4[1] = 2048 * 2048 / 4;
  ca.src[2] = w2; ca.dst[2] = w2b; ca.n4[2] = 160 * 4096 / 4;
  ca.src[3] = w3; ca.dst[3] = w3b; ca.n4[3] = 4096 * 128 / 4;
  ca.src[4] = w4; ca.dst[4] = w4b; ca.n4[4] = 2048 * 4096 / 4;
  cast_multi<<<2048, 256, 0, stream>>>(ca);

  // G1: (M=2048, N=8192, K=2048) -> xib (bf16), rsb = silu(res) (bf16)
  gemmG1<<<dim3(8, 64), 512, 0, stream>>>(
      xb, w1b, xib, rsb, b1, 2048, 8192, 2048);
  // conv + silu (bf16 in/out)
  conv_silu_k<<<dim3(16, 16), 256, 0, stream>>>(xib, cw, cb, xcb);
  // G2 + reduce
  gemm_dbc<<<dim3(32, 8), 256, 0, stream>>>(xcb, w2b, part);
  reduce_dbc<<<1280, 256, 0, stream>>>(part, drb, bcb);
  // G3: delta = softplus(dr @ delta_w^T)
  gemm_bt_sp<<<dim3(16, 32), 256, 0, stream>>>(drb, w3b, delta, 2048, 4096, 128);
  // scan (CHUNK=64 -> 32 chunks)
  scan_passA<<<dim3(16, 32), 256, 0, stream>>>(delta, xcb, bcb, alog, P, S);
  scan_passB<<<256, 256, 0, stream>>>(P, S);
  scan_passC<<<dim3(16, 32), 256, 0, stream>>>(delta, xcb, bcb, alog, P, Dp, rsb, yb);
  // G4: out = y @ out_w^T + b4   (M=2048, N=2048, K=4096) — full-K 128sq
  gemm128_bt<<<dim3(16, 16), 512, 0, stream>>>(yb, w4b, out, b4, 2048, 2048, 4096);
}

// Round 9
// 311.542 us; speedup vs baseline: 1.0340x; 1.0340x over previous
//
#include <hip/hip_runtime.h>
#include <cstdint>
#include <cstddef>

// ---------------------------------------------------------------------------
// MambaBlock on MI355X (gfx950).
// cast_multi -> G1(256sq double-buffer, plain bf16 xr epilogue) -> conv ->
// G2(K-split) -> reduce -> G3(softplus) -> scan(A,B,C; CHUNK=64, silu in C)
// -> G4(128sq double-buffer, fused bias)
// ---------------------------------------------------------------------------

typedef __bf16 bf16x8 __attribute__((ext_vector_type(8)));
typedef float f32x4 __attribute__((ext_vector_type(4)));

#define GLDS16(g, l)                                        \
  __builtin_amdgcn_global_load_lds(                         \
      (__attribute__((address_space(1))) void*)(g),         \
      (__attribute__((address_space(3))) void*)(l), 16, 0, 0)

#define FENCE() asm volatile("" ::: "memory")
#define BARRIER()                      \
  do {                                 \
    FENCE();                           \
    __builtin_amdgcn_s_barrier();      \
    FENCE();                           \
  } while (0)

static __device__ __forceinline__ unsigned short f2b(float f) {
  unsigned int x = __builtin_bit_cast(unsigned int, f);
  x += 0x7fffu + ((x >> 16) & 1u);
  return (unsigned short)(x >> 16);
}

static __device__ __forceinline__ float b2f(unsigned short u) {
  return __builtin_bit_cast(float, (unsigned int)u << 16);
}

static __device__ __forceinline__ float sigmoidf_fast(float x) {
  return 1.0f / (1.0f + __expf(-x));
}

// ---------------- merged cast fp32 -> bf16 (5 segments, one launch) --------
struct CastArgs {
  const float* src[5];
  unsigned short* dst[5];
  int n4[5];
};

__global__ __launch_bounds__(256) void cast_multi(CastArgs a) {
  const int stride = gridDim.x * 256;
  const int t = blockIdx.x * 256 + threadIdx.x;
#pragma unroll
  for (int k = 0; k < 5; ++k) {
    const float4* src = reinterpret_cast<const float4*>(a.src[k]);
    ushort4* dst = reinterpret_cast<ushort4*>(a.dst[k]);
    const int n4 = a.n4[k];
    for (int i = t; i < n4; i += stride) {
      float4 v = src[i];
      ushort4 o;
      o.x = f2b(v.x); o.y = f2b(v.y); o.z = f2b(v.z); o.w = f2b(v.w);
      dst[i] = o;
    }
  }
}

// ---------------- G1: 256x256 tile, BK=64, 8 waves, double buffer ----------
// Round-5 proven schedule (counted vmcnt(8), 2 barriers/K-tile, T2 swizzle,
// T1 XCD swizzle, T5 setprio).  Epilogue: xrb[row][col] = bf16(acc + bias)
// over the full 8192-wide output — no branch, no transcendental.
__global__ __launch_bounds__(512) void gemmG1(
    const unsigned short* __restrict__ A, const unsigned short* __restrict__ B,
    unsigned short* __restrict__ xrb, const float* __restrict__ bias,
    int M, int N, int K) {
  __shared__ __align__(16) unsigned short lds[65536];  // [buf:2][A|B][256][64]
  const int tid = threadIdx.x;
  const int l = tid & 63;
  const int w = tid >> 6;       // 0..7
  const int wr = w >> 2;        // 0..1 -> 128-row half
  const int wc = w & 3;         // 0..3 -> 64-col quarter

  // T1: bijective XCD swizzle (nwg % 8 == 0)
  const int nwg = gridDim.x * gridDim.y;
  const int q = nwg >> 3;
  int flat = blockIdx.x + gridDim.x * blockIdx.y;
  flat = (flat & 7) * q + (flat >> 3);
  const int bx = flat % gridDim.x;
  const int by = flat / gridDim.x;

  const long brow = (long)bx * 256;
  const long bcol = (long)by * 256;
  const int NT = K >> 6;

  f32x4 acc[8][4] = {};

  const unsigned short* Ab = A + (size_t)brow * K;
  const unsigned short* Bb = B + (size_t)bcol * K;
  size_t soff[4];
  int doff[4];
#pragma unroll
  for (int i = 0; i < 4; ++i) {
    int idx = i * 512 + tid;      // 0..2047 -> (row=idx>>3, slot=idx&7)
    int r = idx >> 3, s = idx & 7;
    soff[i] = (size_t)r * K + (size_t)((s ^ (r & 7)) << 3);
    doff[i] = idx * 8;            // ushort offset, 16B per idx
  }

  auto stage = [&](int kt, int buf) {
    const int k0 = kt << 6;
#pragma unroll
    for (int i = 0; i < 4; ++i)
      GLDS16(Ab + soff[i] + k0, &lds[buf * 32768 + doff[i]]);
#pragma unroll
    for (int i = 0; i < 4; ++i)
      GLDS16(Bb + soff[i] + k0, &lds[buf * 32768 + 16384 + doff[i]]);
  };

  const int hi = l >> 4, lo7 = l & 7;
  const int sw0 = ((0 + hi) ^ lo7) << 3;
  const int sw1 = ((4 + hi) ^ lo7) << 3;
  const int rowA = wr * 128 + (l & 15);
  const int colB = wc * 64 + (l & 15);

  stage(0, 0);
  stage(1, 1);

  int buf = 0;
  for (int kt = 0; kt < NT; ++kt) {
    const bool last = (kt == NT - 1);
    if (last) {
      asm volatile("s_waitcnt vmcnt(0)" ::: "memory");
    } else {
      asm volatile("s_waitcnt vmcnt(8)" ::: "memory");
    }
    BARRIER();
    const int bb = buf * 32768;
    bf16x8 a0[8], b0[4];
#pragma unroll
    for (int m = 0; m < 8; ++m)
      a0[m] = *reinterpret_cast<const bf16x8*>(&lds[bb + (rowA + m * 16) * 64 + sw0]);
#pragma unroll
    for (int n = 0; n < 4; ++n)
      b0[n] = *reinterpret_cast<const bf16x8*>(&lds[bb + 16384 + (colB + n * 16) * 64 + sw0]);
    __builtin_amdgcn_s_setprio(1);
#pragma unroll
    for (int m = 0; m < 8; ++m)
#pragma unroll
      for (int n = 0; n < 4; ++n)
        acc[m][n] = __builtin_amdgcn_mfma_f32_16x16x32_bf16(a0[m], b0[n], acc[m][n], 0, 0, 0);
    __builtin_amdgcn_s_setprio(0);
    bf16x8 a1[8], b1[4];
#pragma unroll
    for (int m = 0; m < 8; ++m)
      a1[m] = *reinterpret_cast<const bf16x8*>(&lds[bb + (rowA + m * 16) * 64 + sw1]);
#pragma unroll
    for (int n = 0; n < 4; ++n)
      b1[n] = *reinterpret_cast<const bf16x8*>(&lds[bb + 16384 + (colB + n * 16) * 64 + sw1]);
    asm volatile("s_waitcnt lgkmcnt(0)" ::: "memory");
    __builtin_amdgcn_sched_barrier(0);
    BARRIER();  // all waves done reading this buffer -> safe to overwrite
    if (kt + 2 < NT) stage(kt + 2, buf);
    __builtin_amdgcn_s_setprio(1);
#pragma unroll
    for (int m = 0; m < 8; ++m)
#pragma unroll
      for (int n = 0; n < 4; ++n)
        acc[m][n] = __builtin_amdgcn_mfma_f32_16x16x32_bf16(a1[m], b1[n], acc[m][n], 0, 0, 0);
    __builtin_amdgcn_s_setprio(0);
    buf ^= 1;
  }

  // epilogue: C/D layout col=lane&15, row=(lane>>4)*4+reg; plain bf16 store
  const long r0 = brow + wr * 128 + (l >> 4) * 4;
  const long c0 = bcol + wc * 64 + (l & 15);
#pragma unroll
  for (int m = 0; m < 8; ++m) {
#pragma unroll
    for (int n = 0; n < 4; ++n) {
      const long col = c0 + n * 16;
      const float bv = bias[col];
#pragma unroll
      for (int r = 0; r < 4; ++r)
        xrb[(r0 + m * 16 + r) * (long)N + col] = f2b(acc[m][n][r] + bv);
    }
  }
}

// ---------------- G4: 128x128 tile, BK=64, 8 waves, double buffer ----------
// Round-7 proven: 64KB LDS -> 2 blocks/CU; counted vmcnt(4); fused bias.
__global__ __launch_bounds__(512) void gemm128_bt(
    const unsigned short* __restrict__ A, const unsigned short* __restrict__ B,
    float* __restrict__ C, const float* __restrict__ bias,
    int M, int N, int K) {
  __shared__ __align__(16) unsigned short lds[32768];  // [buf:2][A|B][128][64]
  const int tid = threadIdx.x;
  const int l = tid & 63;
  const int w = tid >> 6;       // 0..7
  const int wr = w >> 2;        // 0..1 -> 64-row half
  const int wc = w & 3;         // 0..3 -> 32-col quarter

  const int nwg = gridDim.x * gridDim.y;
  const int q = nwg >> 3;
  int flat = blockIdx.x + gridDim.x * blockIdx.y;
  flat = (flat & 7) * q + (flat >> 3);
  const int bx = flat % gridDim.x;
  const int by = flat / gridDim.x;

  const long brow = (long)bx * 128;
  const long bcol = (long)by * 128;
  const int NT = K >> 6;

  f32x4 acc[4][2] = {};

  const unsigned short* Ab = A + (size_t)brow * K;
  const unsigned short* Bb = B + (size_t)bcol * K;
  size_t soff[2];
  int doff[2];
#pragma unroll
  for (int i = 0; i < 2; ++i) {
    int idx = i * 512 + tid;      // 0..1023 -> (row=idx>>3, slot=idx&7)
    int r = idx >> 3, s = idx & 7;
    soff[i] = (size_t)r * K + (size_t)((s ^ (r & 7)) << 3);
    doff[i] = idx * 8;
  }

  auto stage = [&](int kt, int buf) {
    const int k0 = kt << 6;
#pragma unroll
    for (int i = 0; i < 2; ++i)
      GLDS16(Ab + soff[i] + k0, &lds[buf * 16384 + doff[i]]);
#pragma unroll
    for (int i = 0; i < 2; ++i)
      GLDS16(Bb + soff[i] + k0, &lds[buf * 16384 + 8192 + doff[i]]);
  };

  const int hi = l >> 4, lo7 = l & 7;
  const int sw0 = ((0 + hi) ^ lo7) << 3;
  const int sw1 = ((4 + hi) ^ lo7) << 3;
  const int rowA = wr * 64 + (l & 15);
  const int colB = wc * 32 + (l & 15);

  stage(0, 0);
  stage(1, 1);

  int buf = 0;
  for (int kt = 0; kt < NT; ++kt) {
    const bool last = (kt == NT - 1);
    if (last) {
      asm volatile("s_waitcnt vmcnt(0)" ::: "memory");
    } else {
      asm volatile("s_waitcnt vmcnt(4)" ::: "memory");
    }
    BARRIER();
    const int bb = buf * 16384;
    bf16x8 a0[4], b0[2];
#pragma unroll
    for (int m = 0; m < 4; ++m)
      a0[m] = *reinterpret_cast<const bf16x8*>(&lds[bb + (rowA + m * 16) * 64 + sw0]);
#pragma unroll
    for (int n = 0; n < 2; ++n)
      b0[n] = *reinterpret_cast<const bf16x8*>(&lds[bb + 8192 + (colB + n * 16) * 64 + sw0]);
    __builtin_amdgcn_s_setprio(1);
#pragma unroll
    for (int m = 0; m < 4; ++m)
#pragma unroll
      for (int n = 0; n < 2; ++n)
        acc[m][n] = __builtin_amdgcn_mfma_f32_16x16x32_bf16(a0[m], b0[n], acc[m][n], 0, 0, 0);
    __builtin_amdgcn_s_setprio(0);
    bf16x8 a1[4], b1[2];
#pragma unroll
    for (int m = 0; m < 4; ++m)
      a1[m] = *reinterpret_cast<const bf16x8*>(&lds[bb + (rowA + m * 16) * 64 + sw1]);
#pragma unroll
    for (int n = 0; n < 2; ++n)
      b1[n] = *reinterpret_cast<const bf16x8*>(&lds[bb + 8192 + (colB + n * 16) * 64 + sw1]);
    asm volatile("s_waitcnt lgkmcnt(0)" ::: "memory");
    __builtin_amdgcn_sched_barrier(0);
    BARRIER();
    if (kt + 2 < NT) stage(kt + 2, buf);
    __builtin_amdgcn_s_setprio(1);
#pragma unroll
    for (int m = 0; m < 4; ++m)
#pragma unroll
      for (int n = 0; n < 2; ++n)
        acc[m][n] = __builtin_amdgcn_mfma_f32_16x16x32_bf16(a1[m], b1[n], acc[m][n], 0, 0, 0);
    __builtin_amdgcn_s_setprio(0);
    buf ^= 1;
  }

  const long r0 = brow + wr * 64 + (l >> 4) * 4;
  const long c0 = bcol + wc * 32 + (l & 15);
#pragma unroll
  for (int m = 0; m < 4; ++m) {
#pragma unroll
    for (int n = 0; n < 2; ++n) {
      long col = c0 + n * 16;
      float bv = bias[col];
#pragma unroll
      for (int r = 0; r < 4; ++r)
        C[(r0 + m * 16 + r) * (long)N + col] = acc[m][n][r] + bv;
    }
  }
}

// ---------------- G3: softplus GEMM (m97 structure, 128x128) ----------------
__global__ __launch_bounds__(256) void gemm_bt_sp(
    const unsigned short* __restrict__ A, const unsigned short* __restrict__ B,
    float* __restrict__ C, int M, int N, int K) {
  __shared__ __align__(16) unsigned short lA[128 * 32];
  __shared__ __align__(16) unsigned short lB[128 * 32];
  const int tid = threadIdx.x;
  const int l = tid & 63;
  const int w = tid >> 6;
  const int wr = w >> 1, wc = w & 1;
  const long brow = (long)blockIdx.x * 128;
  const long bcol = (long)blockIdx.y * 128;

  f32x4 acc[4][4] = {};

  const int srow = tid >> 2;
  const int scol = (tid & 3) * 8;

  const unsigned short* Ab = A + (size_t)brow * K;
  const unsigned short* Bb = B + (size_t)bcol * K;

  for (int k0 = 0; k0 < K; k0 += 32) {
#pragma unroll
    for (int j = 0; j < 2; ++j) {
      GLDS16(Ab + (size_t)(j * 64 + srow) * K + k0 + scol, &lA[j * 2048 + tid * 8]);
      GLDS16(Bb + (size_t)(j * 64 + srow) * K + k0 + scol, &lB[j * 2048 + tid * 8]);
    }
    __syncthreads();
    bf16x8 af[4], bfr[4];
#pragma unroll
    for (int mt = 0; mt < 4; ++mt)
      af[mt] = *reinterpret_cast<const bf16x8*>(
          &lA[(wr * 64 + mt * 16 + (l & 15)) * 32 + (l >> 4) * 8]);
#pragma unroll
    for (int nt = 0; nt < 4; ++nt)
      bfr[nt] = *reinterpret_cast<const bf16x8*>(
          &lB[(wc * 64 + nt * 16 + (l & 15)) * 32 + (l >> 4) * 8]);
#pragma unroll
    for (int mt = 0; mt < 4; ++mt)
#pragma unroll
      for (int nt = 0; nt < 4; ++nt)
        acc[mt][nt] = __builtin_amdgcn_mfma_f32_16x16x32_bf16(
            af[mt], bfr[nt], acc[mt][nt], 0, 0, 0);
    __syncthreads();
  }

  const long r0 = brow + wr * 64 + ((l >> 4) * 4);
  const long c0 = bcol + wc * 64 + (l & 15);
#pragma unroll
  for (int mt = 0; mt < 4; ++mt) {
#pragma unroll
    for (int nt = 0; nt < 4; ++nt) {
      long col = c0 + nt * 16;
#pragma unroll
      for (int r = 0; r < 4; ++r) {
        long row = r0 + mt * 16 + r;
        float v = acc[mt][nt][r];
        v = (v > 20.0f) ? v : log1pf(__expf(v));
        C[row * (long)N + col] = v;
      }
    }
  }
}

// ---------------- depthwise causal conv1d (k=4) + SiLU, bf16 in/out --------
__global__ __launch_bounds__(256) void conv_silu_k(
    const unsigned short* __restrict__ xrb, const float* __restrict__ cw,
    const float* __restrict__ cb, unsigned short* __restrict__ xcb) {
  const int d = blockIdx.x * 256 + threadIdx.x;  // 0..4095
  const int t0 = blockIdx.y * 128;
  const float4 wv = *reinterpret_cast<const float4*>(cw + (size_t)d * 4);
  const float bv = cb[d];
  float xm3 = (t0 >= 3) ? b2f(xrb[(size_t)(t0 - 3) * 8192 + d]) : 0.0f;
  float xm2 = (t0 >= 2) ? b2f(xrb[(size_t)(t0 - 2) * 8192 + d]) : 0.0f;
  float xm1 = (t0 >= 1) ? b2f(xrb[(size_t)(t0 - 1) * 8192 + d]) : 0.0f;
  for (int tt = 0; tt < 128; ++tt) {
    const size_t t = (size_t)t0 + tt;
    float xt = b2f(xrb[t * 8192 + d]);
    float a = bv + wv.x * xm3 + wv.y * xm2 + wv.z * xm1 + wv.w * xt;
    float s = a * sigmoidf_fast(a);
    xcb[t * 4096 + d] = f2b(s);
    xm3 = xm2; xm2 = xm1; xm1 = xt;
  }
}

// ---------------- G2: dbc partials, K-split x8 ----------------
__global__ __launch_bounds__(256) void gemm_dbc(
    const unsigned short* __restrict__ A, const unsigned short* __restrict__ B,
    float* __restrict__ part) {
  __shared__ __align__(16) unsigned short lA[64 * 32];
  __shared__ __align__(16) unsigned short lB[160 * 32];
  const int tid = threadIdx.x;
  const int l = tid & 63, w = tid >> 6;
  const int brow = blockIdx.x * 64;
  const int ks = blockIdx.y;
  const int K = 4096;
  f32x4 acc[10] = {};
  const int srow = tid >> 2, scol = (tid & 3) * 8;
  for (int k0 = ks * 512; k0 < ks * 512 + 512; k0 += 32) {
    GLDS16(A + (size_t)(brow + srow) * K + k0 + scol, &lA[tid * 8]);
#pragma unroll
    for (int j = 0; j < 3; ++j) {
      int li = j * 256 + tid;
      if (li < 640) {
        GLDS16(B + (size_t)(li >> 2) * K + k0 + (li & 3) * 8, &lB[li * 8]);
      }
    }
    __syncthreads();
    bf16x8 af = *reinterpret_cast<const bf16x8*>(
        &lA[(w * 16 + (l & 15)) * 32 + (l >> 4) * 8]);
#pragma unroll
    for (int nt = 0; nt < 10; ++nt) {
      bf16x8 bfr = *reinterpret_cast<const bf16x8*>(
          &lB[(nt * 16 + (l & 15)) * 32 + (l >> 4) * 8]);
      acc[nt] = __builtin_amdgcn_mfma_f32_16x16x32_bf16(af, bfr, acc[nt], 0, 0, 0);
    }
    __syncthreads();
  }
  const int r0 = brow + w * 16 + (l >> 4) * 4;
  const int c = l & 15;
#pragma unroll
  for (int nt = 0; nt < 10; ++nt)
#pragma unroll
    for (int r = 0; r < 4; ++r)
      part[((size_t)ks * 2048 + r0 + r) * 160 + nt * 16 + c] = acc[nt][r];
}

__global__ __launch_bounds__(256) void reduce_dbc(
    const float* __restrict__ part, unsigned short* __restrict__ drb,
    float* __restrict__ bc) {
  int idx = blockIdx.x * 256 + threadIdx.x;
  float s = 0.0f;
#pragma unroll
  for (int k = 0; k < 8; ++k) s += part[(size_t)k * 2048 * 160 + idx];
  int row = idx / 160, col = idx - row * 160;
  if (col < 128) drb[row * 128 + col] = f2b(s);
  else bc[row * 32 + (col - 128)] = s;
}

// ---------------- chunked selective scan (CHUNK=64, u from bf16) -----------
__global__ __launch_bounds__(256) void scan_passA(
    const float* __restrict__ delta, const unsigned short* __restrict__ xcb,
    const float* __restrict__ bc, const float* __restrict__ alog,
    float* __restrict__ P, float* __restrict__ S) {
  __shared__ float lbc[2048];
  const int d = blockIdx.x * 256 + threadIdx.x;
  const int c = blockIdx.y;
  const int t0 = c * 64;
#pragma unroll
  for (int j = 0; j < 8; ++j) {
    int idx = j * 256 + threadIdx.x;
    lbc[idx] = bc[(size_t)t0 * 32 + idx];
  }
  __syncthreads();
  float a[16], h[16], p[16];
#pragma unroll
  for (int s = 0; s < 16; ++s) {
    a[s] = -__expf(alog[(size_t)d * 16 + s]);
    h[s] = 0.0f;
    p[s] = 1.0f;
  }
  for (int tt = 0; tt < 64; ++tt) {
    float dt = delta[(size_t)(t0 + tt) * 4096 + d];
    float u = b2f(xcb[(size_t)(t0 + tt) * 4096 + d]);
    float du = dt * u;
#pragma unroll
    for (int s = 0; s < 16; ++s) {
      float e = __expf(dt * a[s]);
      h[s] = e * h[s] + du * lbc[tt * 32 + s];
      p[s] *= e;
    }
  }
  size_t o = ((size_t)c * 4096 + d) * 16;
#pragma unroll
  for (int s = 0; s < 16; s += 4) {
    *reinterpret_cast<float4*>(&P[o + s]) = make_float4(p[s], p[s + 1], p[s + 2], p[s + 3]);
    *reinterpret_cast<float4*>(&S[o + s]) = make_float4(h[s], h[s + 1], h[s + 2], h[s + 3]);
  }
}

__global__ __launch_bounds__(256) void scan_passB(
    float* __restrict__ P, const float* __restrict__ S) {
  const int idx = blockIdx.x * 256 + threadIdx.x;
  float h = 0.0f;
  for (int c = 0; c < 32; ++c) {
    size_t o = (size_t)c * 65536 + idx;
    float p = P[o], sv = S[o];
    P[o] = h;
    h = p * h + sv;
  }
}

__global__ __launch_bounds__(256) void scan_passC(
    const float* __restrict__ delta, const unsigned short* __restrict__ xcb,
    const float* __restrict__ bc, const float* __restrict__ alog,
    const float* __restrict__ hst, const float* __restrict__ Dp,
    const unsigned short* __restrict__ xrb, unsigned short* __restrict__ yb) {
  __shared__ float lbc[2048];
  const int d = blockIdx.x * 256 + threadIdx.x;
  const int c = blockIdx.y;
  const int t0 = c * 64;
#pragma unroll
  for (int j = 0; j < 8; ++j) {
    int idx = j * 256 + threadIdx.x;
    lbc[idx] = bc[(size_t)t0 * 32 + idx];
  }
  __syncthreads();
  float a[16], h[16];
  size_t o = ((size_t)c * 4096 + d) * 16;
#pragma unroll
  for (int s = 0; s < 16; ++s) {
    a[s] = -__expf(alog[(size_t)d * 16 + s]);
    h[s] = hst[o + s];
  }
  const float Dv = Dp[d];
  for (int tt = 0; tt < 64; ++tt) {
    float dt = delta[(size_t)(t0 + tt) * 4096 + d];
    float u = b2f(xcb[(size_t)(t0 + tt) * 4096 + d]);
    float du = dt * u;
    float y = 0.0f;
#pragma unroll
    for (int s = 0; s < 16; ++s) {
      float e = __expf(dt * a[s]);
      h[s] = e * h[s] + du * lbc[tt * 32 + s];
      y += h[s] * lbc[tt * 32 + 16 + s];
    }
    float res = b2f(xrb[(size_t)(t0 + tt) * 8192 + 4096 + d]);
    float rs = res * sigmoidf_fast(res);
    float v = (y + u * Dv) * rs;
    yb[(size_t)(t0 + tt) * 4096 + d] = f2b(v);
  }
}

// ---------------------------------------------------------------------------
extern "C" void kernel_launch(void* const* d_in, const int* in_sizes, int n_in,
                              void* d_out, int out_size, void* d_ws, size_t ws_size,
                              hipStream_t stream) {
  const float* x    = (const float*)d_in[0];
  const float* w1   = (const float*)d_in[1];
  const float* b1   = (const float*)d_in[2];
  const float* cw   = (const float*)d_in[3];
  const float* cb   = (const float*)d_in[4];
  const float* w2   = (const float*)d_in[5];
  const float* w3   = (const float*)d_in[6];
  const float* alog = (const float*)d_in[7];
  const float* Dp   = (const float*)d_in[8];
  const float* w4   = (const float*)d_in[9];
  const float* b4   = (const float*)d_in[10];
  float* out = (float*)d_out;

  char* ws = (char*)d_ws;
  size_t off = 0;
  auto alloc = [&](size_t b) {
    size_t o = off;
    off += (b + 255) & ~(size_t)255;
    return o;
  };
  unsigned short* w1b = (unsigned short*)(ws + alloc(2ull * 8192 * 2048));
  unsigned short* xb  = (unsigned short*)(ws + alloc(2ull * 2048 * 2048));
  unsigned short* w2b = (unsigned short*)(ws + alloc(2ull * 160 * 4096));
  unsigned short* w3b = (unsigned short*)(ws + alloc(2ull * 4096 * 128));
  unsigned short* w4b = (unsigned short*)(ws + alloc(2ull * 2048 * 4096));
  unsigned short* xrb = (unsigned short*)(ws + alloc(2ull * 2048 * 8192));
  unsigned short* xcb = (unsigned short*)(ws + alloc(2ull * 2048 * 4096));
  unsigned short* drb = (unsigned short*)(ws + alloc(2ull * 2048 * 128));
  float* bcb  = (float*)(ws + alloc(4ull * 2048 * 32));
  float* delta = (float*)(ws + alloc(4ull * 2048 * 4096));
  float* P = (float*)(ws + alloc(4ull * 32 * 4096 * 16));
  float* S = (float*)(ws + alloc(4ull * 32 * 4096 * 16));
  unsigned short* yb = (unsigned short*)(ws + alloc(2ull * 2048 * 4096));
  float* part  = delta;                 // G2 partials (10.5MB), consumed pre-G3

  if (ws_size < off) return;

  CastArgs ca;
  ca.src[0] = w1; ca.dst[0] = w1b; ca.n4[0] = 8192 * 2048 / 4;
  ca.src[1] = x;  ca.dst[1] = xb;  ca.n4[1] = 2048 * 2048 / 4;
  ca.src[2] = w2; ca.dst[2] = w2b; ca.n4[2] = 160 * 4096 / 4;
  ca.src[3] = w3; ca.dst[3] = w3b; ca.n4[3] = 4096 * 128 / 4;
  ca.src[4] = w4; ca.dst[4] = w4b; ca.n4[4] = 2048 * 4096 / 4;
  cast_multi<<<2048, 256, 0, stream>>>(ca);

  // G1: xr = x @ in_proj_w^T + b1 -> bf16 [2048][8192]
  gemmG1<<<dim3(8, 32), 512, 0, stream>>>(xb, w1b, xrb, b1, 2048, 8192, 2048);
  // conv + silu (reads xi = xrb[:, :4096])
  conv_silu_k<<<dim3(16, 16), 256, 0, stream>>>(xrb, cw, cb, xcb);
  // G2 + reduce
  gemm_dbc<<<dim3(32, 8), 256, 0, stream>>>(xcb, w2b, part);
  reduce_dbc<<<1280, 256, 0, stream>>>(part, drb, bcb);
  // G3: delta = softplus(dr @ delta_w^T)
  gemm_bt_sp<<<dim3(16, 32), 256, 0, stream>>>(drb, w3b, delta, 2048, 4096, 128);
  // scan (CHUNK=64 -> 32 chunks); silu(res) computed in passC from xrb
  scan_passA<<<dim3(16, 32), 256, 0, stream>>>(delta, xcb, bcb, alog, P, S);
  scan_passB<<<256, 256, 0, stream>>>(P, S);
  scan_passC<<<dim3(16, 32), 256, 0, stream>>>(delta, xcb, bcb, alog, P, Dp, xrb, yb);
  // G4: out = y @ out_w^T + b4
  gemm128_bt<<<dim3(16, 16), 512, 0, stream>>>(yb, w4b, out, b4, 2048, 2048, 4096);
}

// Round 10
// 275.868 us; speedup vs baseline: 1.1677x; 1.1293x over previous
//
#include <hip/hip_runtime.h>
#include <cstdint>
#include <cstddef>

// ---------------------------------------------------------------------------
// MambaBlock on MI355X (gfx950).
// cast_multi -> G1(256sq double-buffer, plain bf16 xr epilogue) -> conv ->
// G2(K-split) -> reduce -> G3(softplus) -> scan(A,B,C; CHUNK=64, uniform-A
// exp-hoist) -> G4(128sq double-buffer, fused bias)
// ---------------------------------------------------------------------------

typedef __bf16 bf16x8 __attribute__((ext_vector_type(8)));
typedef float f32x4 __attribute__((ext_vector_type(4)));

#define GLDS16(g, l)                                        \
  __builtin_amdgcn_global_load_lds(                         \
      (__attribute__((address_space(1))) void*)(g),         \
      (__attribute__((address_space(3))) void*)(l), 16, 0, 0)

#define FENCE() asm volatile("" ::: "memory")
#define BARRIER()                      \
  do {                                 \
    FENCE();                           \
    __builtin_amdgcn_s_barrier();      \
    FENCE();                           \
  } while (0)

static __device__ __forceinline__ unsigned short f2b(float f) {
  unsigned int x = __builtin_bit_cast(unsigned int, f);
  x += 0x7fffu + ((x >> 16) & 1u);
  return (unsigned short)(x >> 16);
}

static __device__ __forceinline__ float b2f(unsigned short u) {
  return __builtin_bit_cast(float, (unsigned int)u << 16);
}

static __device__ __forceinline__ float sigmoidf_fast(float x) {
  return 1.0f / (1.0f + __expf(-x));
}

// ---------------- merged cast fp32 -> bf16 (5 segments, one launch) --------
struct CastArgs {
  const float* src[5];
  unsigned short* dst[5];
  int n4[5];
};

__global__ __launch_bounds__(256) void cast_multi(CastArgs a) {
  const int stride = gridDim.x * 256;
  const int t = blockIdx.x * 256 + threadIdx.x;
#pragma unroll
  for (int k = 0; k < 5; ++k) {
    const float4* src = reinterpret_cast<const float4*>(a.src[k]);
    ushort4* dst = reinterpret_cast<ushort4*>(a.dst[k]);
    const int n4 = a.n4[k];
    for (int i = t; i < n4; i += stride) {
      float4 v = src[i];
      ushort4 o;
      o.x = f2b(v.x); o.y = f2b(v.y); o.z = f2b(v.z); o.w = f2b(v.w);
      dst[i] = o;
    }
  }
}

// ---------------- G1: 256x256 tile, BK=64, 8 waves, double buffer ----------
__global__ __launch_bounds__(512) void gemmG1(
    const unsigned short* __restrict__ A, const unsigned short* __restrict__ B,
    unsigned short* __restrict__ xrb, const float* __restrict__ bias,
    int M, int N, int K) {
  __shared__ __align__(16) unsigned short lds[65536];  // [buf:2][A|B][256][64]
  const int tid = threadIdx.x;
  const int l = tid & 63;
  const int w = tid >> 6;       // 0..7
  const int wr = w >> 2;        // 0..1 -> 128-row half
  const int wc = w & 3;         // 0..3 -> 64-col quarter

  const int nwg = gridDim.x * gridDim.y;
  const int q = nwg >> 3;
  int flat = blockIdx.x + gridDim.x * blockIdx.y;
  flat = (flat & 7) * q + (flat >> 3);
  const int bx = flat % gridDim.x;
  const int by = flat / gridDim.x;

  const long brow = (long)bx * 256;
  const long bcol = (long)by * 256;
  const int NT = K >> 6;

  f32x4 acc[8][4] = {};

  const unsigned short* Ab = A + (size_t)brow * K;
  const unsigned short* Bb = B + (size_t)bcol * K;
  size_t soff[4];
  int doff[4];
#pragma unroll
  for (int i = 0; i < 4; ++i) {
    int idx = i * 512 + tid;      // 0..2047 -> (row=idx>>3, slot=idx&7)
    int r = idx >> 3, s = idx & 7;
    soff[i] = (size_t)r * K + (size_t)((s ^ (r & 7)) << 3);
    doff[i] = idx * 8;            // ushort offset, 16B per idx
  }

  auto stage = [&](int kt, int buf) {
    const int k0 = kt << 6;
#pragma unroll
    for (int i = 0; i < 4; ++i)
      GLDS16(Ab + soff[i] + k0, &lds[buf * 32768 + doff[i]]);
#pragma unroll
    for (int i = 0; i < 4; ++i)
      GLDS16(Bb + soff[i] + k0, &lds[buf * 32768 + 16384 + doff[i]]);
  };

  const int hi = l >> 4, lo7 = l & 7;
  const int sw0 = ((0 + hi) ^ lo7) << 3;
  const int sw1 = ((4 + hi) ^ lo7) << 3;
  const int rowA = wr * 128 + (l & 15);
  const int colB = wc * 64 + (l & 15);

  stage(0, 0);
  stage(1, 1);

  int buf = 0;
  for (int kt = 0; kt < NT; ++kt) {
    const bool last = (kt == NT - 1);
    if (last) {
      asm volatile("s_waitcnt vmcnt(0)" ::: "memory");
    } else {
      asm volatile("s_waitcnt vmcnt(8)" ::: "memory");
    }
    BARRIER();
    const int bb = buf * 32768;
    bf16x8 a0[8], b0[4];
#pragma unroll
    for (int m = 0; m < 8; ++m)
      a0[m] = *reinterpret_cast<const bf16x8*>(&lds[bb + (rowA + m * 16) * 64 + sw0]);
#pragma unroll
    for (int n = 0; n < 4; ++n)
      b0[n] = *reinterpret_cast<const bf16x8*>(&lds[bb + 16384 + (colB + n * 16) * 64 + sw0]);
    __builtin_amdgcn_s_setprio(1);
#pragma unroll
    for (int m = 0; m < 8; ++m)
#pragma unroll
      for (int n = 0; n < 4; ++n)
        acc[m][n] = __builtin_amdgcn_mfma_f32_16x16x32_bf16(a0[m], b0[n], acc[m][n], 0, 0, 0);
    __builtin_amdgcn_s_setprio(0);
    bf16x8 a1[8], b1[4];
#pragma unroll
    for (int m = 0; m < 8; ++m)
      a1[m] = *reinterpret_cast<const bf16x8*>(&lds[bb + (rowA + m * 16) * 64 + sw1]);
#pragma unroll
    for (int n = 0; n < 4; ++n)
      b1[n] = *reinterpret_cast<const bf16x8*>(&lds[bb + 16384 + (colB + n * 16) * 64 + sw1]);
    asm volatile("s_waitcnt lgkmcnt(0)" ::: "memory");
    __builtin_amdgcn_sched_barrier(0);
    BARRIER();  // all waves done reading this buffer -> safe to overwrite
    if (kt + 2 < NT) stage(kt + 2, buf);
    __builtin_amdgcn_s_setprio(1);
#pragma unroll
    for (int m = 0; m < 8; ++m)
#pragma unroll
      for (int n = 0; n < 4; ++n)
        acc[m][n] = __builtin_amdgcn_mfma_f32_16x16x32_bf16(a1[m], b1[n], acc[m][n], 0, 0, 0);
    __builtin_amdgcn_s_setprio(0);
    buf ^= 1;
  }

  const long r0 = brow + wr * 128 + (l >> 4) * 4;
  const long c0 = bcol + wc * 64 + (l & 15);
#pragma unroll
  for (int m = 0; m < 8; ++m) {
#pragma unroll
    for (int n = 0; n < 4; ++n) {
      const long col = c0 + n * 16;
      const float bv = bias[col];
#pragma unroll
      for (int r = 0; r < 4; ++r)
        xrb[(r0 + m * 16 + r) * (long)N + col] = f2b(acc[m][n][r] + bv);
    }
  }
}

// ---------------- G4: 128x128 tile, BK=64, 8 waves, double buffer ----------
__global__ __launch_bounds__(512) void gemm128_bt(
    const unsigned short* __restrict__ A, const unsigned short* __restrict__ B,
    float* __restrict__ C, const float* __restrict__ bias,
    int M, int N, int K) {
  __shared__ __align__(16) unsigned short lds[32768];  // [buf:2][A|B][128][64]
  const int tid = threadIdx.x;
  const int l = tid & 63;
  const int w = tid >> 6;       // 0..7
  const int wr = w >> 2;        // 0..1 -> 64-row half
  const int wc = w & 3;         // 0..3 -> 32-col quarter

  const int nwg = gridDim.x * gridDim.y;
  const int q = nwg >> 3;
  int flat = blockIdx.x + gridDim.x * blockIdx.y;
  flat = (flat & 7) * q + (flat >> 3);
  const int bx = flat % gridDim.x;
  const int by = flat / gridDim.x;

  const long brow = (long)bx * 128;
  const long bcol = (long)by * 128;
  const int NT = K >> 6;

  f32x4 acc[4][2] = {};

  const unsigned short* Ab = A + (size_t)brow * K;
  const unsigned short* Bb = B + (size_t)bcol * K;
  size_t soff[2];
  int doff[2];
#pragma unroll
  for (int i = 0; i < 2; ++i) {
    int idx = i * 512 + tid;      // 0..1023 -> (row=idx>>3, slot=idx&7)
    int r = idx >> 3, s = idx & 7;
    soff[i] = (size_t)r * K + (size_t)((s ^ (r & 7)) << 3);
    doff[i] = idx * 8;
  }

  auto stage = [&](int kt, int buf) {
    const int k0 = kt << 6;
#pragma unroll
    for (int i = 0; i < 2; ++i)
      GLDS16(Ab + soff[i] + k0, &lds[buf * 16384 + doff[i]]);
#pragma unroll
    for (int i = 0; i < 2; ++i)
      GLDS16(Bb + soff[i] + k0, &lds[buf * 16384 + 8192 + doff[i]]);
  };

  const int hi = l >> 4, lo7 = l & 7;
  const int sw0 = ((0 + hi) ^ lo7) << 3;
  const int sw1 = ((4 + hi) ^ lo7) << 3;
  const int rowA = wr * 64 + (l & 15);
  const int colB = wc * 32 + (l & 15);

  stage(0, 0);
  stage(1, 1);

  int buf = 0;
  for (int kt = 0; kt < NT; ++kt) {
    const bool last = (kt == NT - 1);
    if (last) {
      asm volatile("s_waitcnt vmcnt(0)" ::: "memory");
    } else {
      asm volatile("s_waitcnt vmcnt(4)" ::: "memory");
    }
    BARRIER();
    const int bb = buf * 16384;
    bf16x8 a0[4], b0[2];
#pragma unroll
    for (int m = 0; m < 4; ++m)
      a0[m] = *reinterpret_cast<const bf16x8*>(&lds[bb + (rowA + m * 16) * 64 + sw0]);
#pragma unroll
    for (int n = 0; n < 2; ++n)
      b0[n] = *reinterpret_cast<const bf16x8*>(&lds[bb + 8192 + (colB + n * 16) * 64 + sw0]);
    __builtin_amdgcn_s_setprio(1);
#pragma unroll
    for (int m = 0; m < 4; ++m)
#pragma unroll
      for (int n = 0; n < 2; ++n)
        acc[m][n] = __builtin_amdgcn_mfma_f32_16x16x32_bf16(a0[m], b0[n], acc[m][n], 0, 0, 0);
    __builtin_amdgcn_s_setprio(0);
    bf16x8 a1[4], b1[2];
#pragma unroll
    for (int m = 0; m < 4; ++m)
      a1[m] = *reinterpret_cast<const bf16x8*>(&lds[bb + (rowA + m * 16) * 64 + sw1]);
#pragma unroll
    for (int n = 0; n < 2; ++n)
      b1[n] = *reinterpret_cast<const bf16x8*>(&lds[bb + 8192 + (colB + n * 16) * 64 + sw1]);
    asm volatile("s_waitcnt lgkmcnt(0)" ::: "memory");
    __builtin_amdgcn_sched_barrier(0);
    BARRIER();
    if (kt + 2 < NT) stage(kt + 2, buf);
    __builtin_amdgcn_s_setprio(1);
#pragma unroll
    for (int m = 0; m < 4; ++m)
#pragma unroll
      for (int n = 0; n < 2; ++n)
        acc[m][n] = __builtin_amdgcn_mfma_f32_16x16x32_bf16(a1[m], b1[n], acc[m][n], 0, 0, 0);
    __builtin_amdgcn_s_setprio(0);
    buf ^= 1;
  }

  const long r0 = brow + wr * 64 + (l >> 4) * 4;
  const long c0 = bcol + wc * 32 + (l & 15);
#pragma unroll
  for (int m = 0; m < 4; ++m) {
#pragma unroll
    for (int n = 0; n < 2; ++n) {
      long col = c0 + n * 16;
      float bv = bias[col];
#pragma unroll
      for (int r = 0; r < 4; ++r)
        C[(r0 + m * 16 + r) * (long)N + col] = acc[m][n][r] + bv;
    }
  }
}

// ---------------- G3: softplus GEMM (m97 structure, 128x128) ----------------
__global__ __launch_bounds__(256) void gemm_bt_sp(
    const unsigned short* __restrict__ A, const unsigned short* __restrict__ B,
    float* __restrict__ C, int M, int N, int K) {
  __shared__ __align__(16) unsigned short lA[128 * 32];
  __shared__ __align__(16) unsigned short lB[128 * 32];
  const int tid = threadIdx.x;
  const int l = tid & 63;
  const int w = tid >> 6;
  const int wr = w >> 1, wc = w & 1;
  const long brow = (long)blockIdx.x * 128;
  const long bcol = (long)blockIdx.y * 128;

  f32x4 acc[4][4] = {};

  const int srow = tid >> 2;
  const int scol = (tid & 3) * 8;

  const unsigned short* Ab = A + (size_t)brow * K;
  const unsigned short* Bb = B + (size_t)bcol * K;

  for (int k0 = 0; k0 < K; k0 += 32) {
#pragma unroll
    for (int j = 0; j < 2; ++j) {
      GLDS16(Ab + (size_t)(j * 64 + srow) * K + k0 + scol, &lA[j * 2048 + tid * 8]);
      GLDS16(Bb + (size_t)(j * 64 + srow) * K + k0 + scol, &lB[j * 2048 + tid * 8]);
    }
    __syncthreads();
    bf16x8 af[4], bfr[4];
#pragma unroll
    for (int mt = 0; mt < 4; ++mt)
      af[mt] = *reinterpret_cast<const bf16x8*>(
          &lA[(wr * 64 + mt * 16 + (l & 15)) * 32 + (l >> 4) * 8]);
#pragma unroll
    for (int nt = 0; nt < 4; ++nt)
      bfr[nt] = *reinterpret_cast<const bf16x8*>(
          &lB[(wc * 64 + nt * 16 + (l & 15)) * 32 + (l >> 4) * 8]);
#pragma unroll
    for (int mt = 0; mt < 4; ++mt)
#pragma unroll
      for (int nt = 0; nt < 4; ++nt)
        acc[mt][nt] = __builtin_amdgcn_mfma_f32_16x16x32_bf16(
            af[mt], bfr[nt], acc[mt][nt], 0, 0, 0);
    __syncthreads();
  }

  const long r0 = brow + wr * 64 + ((l >> 4) * 4);
  const long c0 = bcol + wc * 64 + (l & 15);
#pragma unroll
  for (int mt = 0; mt < 4; ++mt) {
#pragma unroll
    for (int nt = 0; nt < 4; ++nt) {
      long col = c0 + nt * 16;
#pragma unroll
      for (int r = 0; r < 4; ++r) {
        long row = r0 + mt * 16 + r;
        float v = acc[mt][nt][r];
        v = (v > 20.0f) ? v : log1pf(__expf(v));
        C[row * (long)N + col] = v;
      }
    }
  }
}

// ---------------- depthwise causal conv1d (k=4) + SiLU, bf16 in/out --------
__global__ __launch_bounds__(256) void conv_silu_k(
    const unsigned short* __restrict__ xrb, const float* __restrict__ cw,
    const float* __restrict__ cb, unsigned short* __restrict__ xcb) {
  const int d = blockIdx.x * 256 + threadIdx.x;  // 0..4095
  const int t0 = blockIdx.y * 128;
  const float4 wv = *reinterpret_cast<const float4*>(cw + (size_t)d * 4);
  const float bv = cb[d];
  float xm3 = (t0 >= 3) ? b2f(xrb[(size_t)(t0 - 3) * 8192 + d]) : 0.0f;
  float xm2 = (t0 >= 2) ? b2f(xrb[(size_t)(t0 - 2) * 8192 + d]) : 0.0f;
  float xm1 = (t0 >= 1) ? b2f(xrb[(size_t)(t0 - 1) * 8192 + d]) : 0.0f;
  for (int tt = 0; tt < 128; ++tt) {
    const size_t t = (size_t)t0 + tt;
    float xt = b2f(xrb[t * 8192 + d]);
    float a = bv + wv.x * xm3 + wv.y * xm2 + wv.z * xm1 + wv.w * xt;
    float s = a * sigmoidf_fast(a);
    xcb[t * 4096 + d] = f2b(s);
    xm3 = xm2; xm2 = xm1; xm1 = xt;
  }
}

// ---------------- G2: dbc partials, K-split x8 ----------------
__global__ __launch_bounds__(256) void gemm_dbc(
    const unsigned short* __restrict__ A, const unsigned short* __restrict__ B,
    float* __restrict__ part) {
  __shared__ __align__(16) unsigned short lA[64 * 32];
  __shared__ __align__(16) unsigned short lB[160 * 32];
  const int tid = threadIdx.x;
  const int l = tid & 63, w = tid >> 6;
  const int brow = blockIdx.x * 64;
  const int ks = blockIdx.y;
  const int K = 4096;
  f32x4 acc[10] = {};
  const int srow = tid >> 2, scol = (tid & 3) * 8;
  for (int k0 = ks * 512; k0 < ks * 512 + 512; k0 += 32) {
    GLDS16(A + (size_t)(brow + srow) * K + k0 + scol, &lA[tid * 8]);
#pragma unroll
    for (int j = 0; j < 3; ++j) {
      int li = j * 256 + tid;
      if (li < 640) {
        GLDS16(B + (size_t)(li >> 2) * K + k0 + (li & 3) * 8, &lB[li * 8]);
      }
    }
    __syncthreads();
    bf16x8 af = *reinterpret_cast<const bf16x8*>(
        &lA[(w * 16 + (l & 15)) * 32 + (l >> 4) * 8]);
#pragma unroll
    for (int nt = 0; nt < 10; ++nt) {
      bf16x8 bfr = *reinterpret_cast<const bf16x8*>(
          &lB[(nt * 16 + (l & 15)) * 32 + (l >> 4) * 8]);
      acc[nt] = __builtin_amdgcn_mfma_f32_16x16x32_bf16(af, bfr, acc[nt], 0, 0, 0);
    }
    __syncthreads();
  }
  const int r0 = brow + w * 16 + (l >> 4) * 4;
  const int c = l & 15;
#pragma unroll
  for (int nt = 0; nt < 10; ++nt)
#pragma unroll
    for (int r = 0; r < 4; ++r)
      part[((size_t)ks * 2048 + r0 + r) * 160 + nt * 16 + c] = acc[nt][r];
}

__global__ __launch_bounds__(256) void reduce_dbc(
    const float* __restrict__ part, unsigned short* __restrict__ drb,
    float* __restrict__ bc) {
  int idx = blockIdx.x * 256 + threadIdx.x;
  float s = 0.0f;
#pragma unroll
  for (int k = 0; k < 8; ++k) s += part[(size_t)k * 2048 * 160 + idx];
  int row = idx / 160, col = idx - row * 160;
  if (col < 128) drb[row * 128 + col] = f2b(s);
  else bc[row * 32 + (col - 128)] = s;
}

// ---------------- chunked selective scan (CHUNK=64, uniform-A exp hoist) ---
// A_log rows are constant across the 16 states for this model's init
// (repeat(arange)), so exp(dt*a[s]) is one exp per (t,d).  Runtime guard
// keeps the kernel correct for arbitrary A_log (uniform check per d).
__global__ __launch_bounds__(256) void scan_passA(
    const float* __restrict__ delta, const unsigned short* __restrict__ xcb,
    const float* __restrict__ bc, const float* __restrict__ alog,
    float* __restrict__ P, float* __restrict__ S) {
  __shared__ float lbc[2048];
  const int d = blockIdx.x * 256 + threadIdx.x;
  const int c = blockIdx.y;
  const int t0 = c * 64;
#pragma unroll
  for (int j = 0; j < 8; ++j) {
    int idx = j * 256 + threadIdx.x;
    lbc[idx] = bc[(size_t)t0 * 32 + idx];
  }
  __syncthreads();
  float a[16], h[16];
  bool uni = true;
  const float al0 = alog[(size_t)d * 16];
#pragma unroll
  for (int s = 0; s < 16; ++s) {
    float al = alog[(size_t)d * 16 + s];
    uni = uni && (al == al0);
    a[s] = -__expf(al);
    h[s] = 0.0f;
  }
  size_t o = ((size_t)c * 4096 + d) * 16;
  if (uni) {
    float p0 = 1.0f;
    for (int tt = 0; tt < 64; ++tt) {
      float dt = delta[(size_t)(t0 + tt) * 4096 + d];
      float u = b2f(xcb[(size_t)(t0 + tt) * 4096 + d]);
      float du = dt * u;
      float e = __expf(dt * a[0]);
      p0 *= e;
#pragma unroll
      for (int s = 0; s < 16; ++s)
        h[s] = e * h[s] + du * lbc[tt * 32 + s];
    }
#pragma unroll
    for (int s = 0; s < 16; s += 4) {
      *reinterpret_cast<float4*>(&P[o + s]) = make_float4(p0, p0, p0, p0);
      *reinterpret_cast<float4*>(&S[o + s]) = make_float4(h[s], h[s + 1], h[s + 2], h[s + 3]);
    }
  } else {
    float p[16];
#pragma unroll
    for (int s = 0; s < 16; ++s) p[s] = 1.0f;
    for (int tt = 0; tt < 64; ++tt) {
      float dt = delta[(size_t)(t0 + tt) * 4096 + d];
      float u = b2f(xcb[(size_t)(t0 + tt) * 4096 + d]);
      float du = dt * u;
#pragma unroll
      for (int s = 0; s < 16; ++s) {
        float e = __expf(dt * a[s]);
        h[s] = e * h[s] + du * lbc[tt * 32 + s];
        p[s] *= e;
      }
    }
#pragma unroll
    for (int s = 0; s < 16; s += 4) {
      *reinterpret_cast<float4*>(&P[o + s]) = make_float4(p[s], p[s + 1], p[s + 2], p[s + 3]);
      *reinterpret_cast<float4*>(&S[o + s]) = make_float4(h[s], h[s + 1], h[s + 2], h[s + 3]);
    }
  }
}

__global__ __launch_bounds__(256) void scan_passB(
    float* __restrict__ P, const float* __restrict__ S) {
  const int idx = blockIdx.x * 256 + threadIdx.x;
  float h = 0.0f;
  for (int c = 0; c < 32; ++c) {
    size_t o = (size_t)c * 65536 + idx;
    float p = P[o], sv = S[o];
    P[o] = h;
    h = p * h + sv;
  }
}

__global__ __launch_bounds__(256) void scan_passC(
    const float* __restrict__ delta, const unsigned short* __restrict__ xcb,
    const float* __restrict__ bc, const float* __restrict__ alog,
    const float* __restrict__ hst, const float* __restrict__ Dp,
    const unsigned short* __restrict__ xrb, unsigned short* __restrict__ yb) {
  __shared__ float lbc[2048];
  const int d = blockIdx.x * 256 + threadIdx.x;
  const int c = blockIdx.y;
  const int t0 = c * 64;
#pragma unroll
  for (int j = 0; j < 8; ++j) {
    int idx = j * 256 + threadIdx.x;
    lbc[idx] = bc[(size_t)t0 * 32 + idx];
  }
  __syncthreads();
  float a[16], h[16];
  bool uni = true;
  const float al0 = alog[(size_t)d * 16];
  size_t o = ((size_t)c * 4096 + d) * 16;
#pragma unroll
  for (int s = 0; s < 16; ++s) {
    float al = alog[(size_t)d * 16 + s];
    uni = uni && (al == al0);
    a[s] = -__expf(al);
    h[s] = hst[o + s];
  }
  const float Dv = Dp[d];
  if (uni) {
    for (int tt = 0; tt < 64; ++tt) {
      float dt = delta[(size_t)(t0 + tt) * 4096 + d];
      float u = b2f(xcb[(size_t)(t0 + tt) * 4096 + d]);
      float du = dt * u;
      float e = __expf(dt * a[0]);
      float y = 0.0f;
#pragma unroll
      for (int s = 0; s < 16; ++s) {
        h[s] = e * h[s] + du * lbc[tt * 32 + s];
        y += h[s] * lbc[tt * 32 + 16 + s];
      }
      float res = b2f(xrb[(size_t)(t0 + tt) * 8192 + 4096 + d]);
      float rs = res * sigmoidf_fast(res);
      float v = (y + u * Dv) * rs;
      yb[(size_t)(t0 + tt) * 4096 + d] = f2b(v);
    }
  } else {
    for (int tt = 0; tt < 64; ++tt) {
      float dt = delta[(size_t)(t0 + tt) * 4096 + d];
      float u = b2f(xcb[(size_t)(t0 + tt) * 4096 + d]);
      float du = dt * u;
      float y = 0.0f;
#pragma unroll
      for (int s = 0; s < 16; ++s) {
        float e = __expf(dt * a[s]);
        h[s] = e * h[s] + du * lbc[tt * 32 + s];
        y += h[s] * lbc[tt * 32 + 16 + s];
      }
      float res = b2f(xrb[(size_t)(t0 + tt) * 8192 + 4096 + d]);
      float rs = res * sigmoidf_fast(res);
      float v = (y + u * Dv) * rs;
      yb[(size_t)(t0 + tt) * 4096 + d] = f2b(v);
    }
  }
}

// ---------------------------------------------------------------------------
extern "C" void kernel_launch(void* const* d_in, const int* in_sizes, int n_in,
                              void* d_out, int out_size, void* d_ws, size_t ws_size,
                              hipStream_t stream) {
  const float* x    = (const float*)d_in[0];
  const float* w1   = (const float*)d_in[1];
  const float* b1   = (const float*)d_in[2];
  const float* cw   = (const float*)d_in[3];
  const float* cb   = (const float*)d_in[4];
  const float* w2   = (const float*)d_in[5];
  const float* w3   = (const float*)d_in[6];
  const float* alog = (const float*)d_in[7];
  const float* Dp   = (const float*)d_in[8];
  const float* w4   = (const float*)d_in[9];
  const float* b4   = (const float*)d_in[10];
  float* out = (float*)d_out;

  char* ws = (char*)d_ws;
  size_t off = 0;
  auto alloc = [&](size_t b) {
    size_t o = off;
    off += (b + 255) & ~(size_t)255;
    return o;
  };
  unsigned short* w1b = (unsigned short*)(ws + alloc(2ull * 8192 * 2048));
  unsigned short* xb  = (unsigned short*)(ws + alloc(2ull * 2048 * 2048));
  unsigned short* w2b = (unsigned short*)(ws + alloc(2ull * 160 * 4096));
  unsigned short* w3b = (unsigned short*)(ws + alloc(2ull * 4096 * 128));
  unsigned short* w4b = (unsigned short*)(ws + alloc(2ull * 2048 * 4096));
  unsigned short* xrb = (unsigned short*)(ws + alloc(2ull * 2048 * 8192));
  unsigned short* xcb = (unsigned short*)(ws + alloc(2ull * 2048 * 4096));
  unsigned short* drb = (unsigned short*)(ws + alloc(2ull * 2048 * 128));
  float* bcb  = (float*)(ws + alloc(4ull * 2048 * 32));
  float* delta = (float*)(ws + alloc(4ull * 2048 * 4096));
  float* P = (float*)(ws + alloc(4ull * 32 * 4096 * 16));
  float* S = (float*)(ws + alloc(4ull * 32 * 4096 * 16));
  unsigned short* yb = (unsigned short*)(ws + alloc(2ull * 2048 * 4096));
  float* part  = delta;                 // G2 partials (10.5MB), consumed pre-G3

  if (ws_size < off) return;

  CastArgs ca;
  ca.src[0] = w1; ca.dst[0] = w1b; ca.n4[0] = 8192 * 2048 / 4;
  ca.src[1] = x;  ca.dst[1] = xb;  ca.n4[1] = 2048 * 2048 / 4;
  ca.src[2] = w2; ca.dst[2] = w2b; ca.n4[2] = 160 * 4096 / 4;
  ca.src[3] = w3; ca.dst[3] = w3b; ca.n4[3] = 4096 * 128 / 4;
  ca.src[4] = w4; ca.dst[4] = w4b; ca.n4[4] = 2048 * 4096 / 4;
  cast_multi<<<2048, 256, 0, stream>>>(ca);

  // G1: xr = x @ in_proj_w^T + b1 -> bf16 [2048][8192]
  gemmG1<<<dim3(8, 32), 512, 0, stream>>>(xb, w1b, xrb, b1, 2048, 8192, 2048);
  // conv + silu (reads xi = xrb[:, :4096])
  conv_silu_k<<<dim3(16, 16), 256, 0, stream>>>(xrb, cw, cb, xcb);
  // G2 + reduce
  gemm_dbc<<<dim3(32, 8), 256, 0, stream>>>(xcb, w2b, part);
  reduce_dbc<<<1280, 256, 0, stream>>>(part, drb, bcb);
  // G3: delta = softplus(dr @ delta_w^T)
  gemm_bt_sp<<<dim3(16, 32), 256, 0, stream>>>(drb, w3b, delta, 2048, 4096, 128);
  // scan (CHUNK=64 -> 32 chunks); silu(res) computed in passC from xrb
  scan_passA<<<dim3(16, 32), 256, 0, stream>>>(delta, xcb, bcb, alog, P, S);
  scan_passB<<<256, 256, 0, stream>>>(P, S);
  scan_passC<<<dim3(16, 32), 256, 0, stream>>>(delta, xcb, bcb, alog, P, Dp, xrb, yb);
  // G4: out = y @ out_w^T + b4
  gemm128_bt<<<dim3(16, 16), 512, 0, stream>>>(yb, w4b, out, b4, 2048, 2048, 4096);
}